// Round 10
// baseline (281.298 us; speedup 1.0000x reference)
//
#include <hip/hip_runtime.h>
#include <hip/hip_bf16.h>

// Problem constants (from reference)
#define BATCH 16384
#define DIM   128
#define HID   1024
#define NK    8
#define OPD   25          // 3*K+1
#define N3    (DIM*OPD)   // 3200
#define NP    3328        // 26 tiles x 128 cols; tile = 5 dims x 25 params + 3 pad

typedef __attribute__((ext_vector_type(8))) short  short8;   // 8 bf16 (4 VGPRs)
typedef __attribute__((ext_vector_type(4))) float  floatx4;  // MFMA C/D frag
typedef unsigned int u32;

// fast-math scalar helpers (single v_exp / v_log / v_rcp)
__device__ __forceinline__ float fexp(float x) { return __expf(x); }
__device__ __forceinline__ float flog(float x) { return __logf(x); }
__device__ __forceinline__ float fdiv(float a, float b) { return __fdividef(a, b); }

// async global->LDS, 16B per lane. dst = wave-uniform base + lane*16.
__device__ __forceinline__ void async_copy16(const unsigned short* g,
                                             unsigned short* l) {
    __builtin_amdgcn_global_load_lds(
        (const __attribute__((address_space(1))) u32*)g,
        (__attribute__((address_space(3))) u32*)l,
        16, 0, 0);
}

// ---------------------------------------------------------------- pre kernel
// One dispatch: h1 row-reduces, h2 column sums, x->bf16 cast, lad init.
// blocks [0,512): h1 rows 2b,2b+1 | [512,516): h2 cols | [516, 516+8192): x/lad
__global__ __launch_bounds__(256) void pre_kernel(
    const float* __restrict__ m1, const float* __restrict__ m3,
    const float* __restrict__ x,
    int* __restrict__ h1i, int* __restrict__ h2i,
    __hip_bfloat16* __restrict__ xb, float* __restrict__ lad)
{
    const int b = blockIdx.x, t = threadIdx.x;
    if (b < 512) {
        const int row = 2 * b + (t >> 7);
        const int col = t & 127;
        float v = m1[row * DIM + col];
        #pragma unroll
        for (int off = 32; off > 0; off >>= 1) v += __shfl_down(v, off, 64);
        __shared__ float ws[4];
        if ((t & 63) == 0) ws[t >> 6] = v;
        __syncthreads();
        if (t == 0)   h1i[2 * b]     = (int)(ws[0] + ws[1] + 0.5f);
        if (t == 128) h1i[2 * b + 1] = (int)(ws[2] + ws[3] + 0.5f);
    } else if (b < 516) {
        const int j = (b - 512) * 256 + t;
        float s = 0.f;
        for (int d = 0; d < DIM; d++) s += m3[(size_t)d * OPD * HID + j];
        h2i[j] = DIM - (int)(s + 0.5f);
    } else {
        const int i = (b - 516) * 256 + t;
        xb[i] = __float2bfloat16(x[i]);
        if (i < BATCH) lad[i] = 0.f;
    }
}

// Counting sort (layer1 by h1, layer2 by h2) + per-tile K bounds. Skipped
// K-region is exact zeros -> bit-identical.
__global__ __launch_bounds__(1024) void sort_kernel(
    const int* __restrict__ h1i, const int* __restrict__ h2i,
    int* __restrict__ perm1, int* __restrict__ perm2,
    int* __restrict__ h1sv, int* __restrict__ h2sv,
    int* __restrict__ klim1, int* __restrict__ klim2, int* __restrict__ klim3)
{
    __shared__ int hist[128];
    __shared__ int h1s[1024], h2s[1024];
    const int t = threadIdx.x;
    const int h1v = h1i[t], h2v = h2i[t];

    if (t < 128) hist[t] = 0;
    __syncthreads();
    atomicAdd(&hist[h1v], 1);
    __syncthreads();
    if (t == 0) { int a = 0; for (int b = 0; b < 128; b++) { int c = hist[b]; hist[b] = a; a += c; } }
    __syncthreads();
    int r = atomicAdd(&hist[h1v], 1);
    perm1[r] = t; h1s[r] = h1v; h1sv[r] = h1v;
    __syncthreads();
    if (t < 128) hist[t] = 0;
    __syncthreads();
    atomicAdd(&hist[h2v], 1);
    __syncthreads();
    if (t == 0) { int a = 0; for (int b = 0; b < 128; b++) { int c = hist[b]; hist[b] = a; a += c; } }
    __syncthreads();
    r = atomicAdd(&hist[h2v], 1);
    perm2[r] = t; h2s[r] = h2v; h2sv[r] = h2v;
    __syncthreads();

    if (t < 8) {
        klim1[t] = ((h1s[t * 128 + 127] + 63) >> 6) << 6;
        int mh = h2s[t * 128 + 127];
        int c = 0;
        for (int j = 0; j < 1024; j++) c += (h1s[j] <= mh) ? 1 : 0;
        klim2[t] = ((c + 63) >> 6) << 6;
    }
    if (t < 26) {
        int dmax = t * 5 + 4; if (dmax > 127) dmax = 127;
        int c = 0;
        for (int j = 0; j < 1024; j++) c += (h2s[j] <= dmax) ? 1 : 0;
        klim3[t] = ((c + 63) >> 6) << 6;
    }
}

// ---------------------------------------------------------------- megaprep
// One dispatch: w2p rows [0,HID), w3p rows [HID,HID+NP), w1p [HID+NP, +512).
// Masks recomputed from sorted h-values (exact): m1=(col<h1sv), m2=(h1sv<=h2sv),
// m3=(h2sv<=d).
__global__ __launch_bounds__(256) void megaprep_kernel(
    const float* __restrict__ W1, const float* __restrict__ b1,
    const float* __restrict__ W2, const float* __restrict__ b2,
    const float* __restrict__ W3,
    const int* __restrict__ perm1, const int* __restrict__ perm2,
    const int* __restrict__ h1sv, const int* __restrict__ h2sv,
    __hip_bfloat16* __restrict__ w1p, float* __restrict__ b1p,
    __hip_bfloat16* __restrict__ w2p, float* __restrict__ b2p,
    __hip_bfloat16* __restrict__ w3p)
{
    __shared__ float row[HID];
    const int b = blockIdx.x, t = threadIdx.x;
    if (b < HID) {                       // ---- w2p row b
        const int si = perm2[b];
        const int h2v = h2sv[b];
        #pragma unroll
        for (int q = 0; q < 4; q++) row[q * 256 + t] = W2[(size_t)si * HID + q * 256 + t];
        __syncthreads();
        #pragma unroll
        for (int q = 0; q < 4; q++) {
            const int jp = q * 256 + t;
            float v = (h1sv[jp] <= h2v) ? row[perm1[jp]] : 0.f;
            w2p[(size_t)b * HID + jp] = __float2bfloat16(v);
        }
        if (t == 0) b2p[b] = b2[si];
    } else if (b < HID + NP) {           // ---- w3p row c
        const int c = b - HID;
        const int s = c & 127, t3 = c >> 7;
        if (s >= 125) {
            #pragma unroll
            for (int q = 0; q < 4; q++)
                w3p[(size_t)c * HID + q * 256 + t] = __float2bfloat16(0.f);
            return;
        }
        const int srcrow = t3 * 125 + s;
        const int d = srcrow / 25;
        #pragma unroll
        for (int q = 0; q < 4; q++) row[q * 256 + t] = W3[(size_t)srcrow * HID + q * 256 + t];
        __syncthreads();
        #pragma unroll
        for (int q = 0; q < 4; q++) {
            const int kk = q * 256 + t;
            float v = (h2sv[kk] <= d) ? row[perm2[kk]] : 0.f;
            w3p[(size_t)c * HID + kk] = __float2bfloat16(v);
        }
    } else {                             // ---- w1p flat
        const int i = (b - HID - NP) * 256 + t;   // over HID*DIM
        const int hp = i >> 7, col = i & 127;
        const int src = perm1[hp];
        float v = (col < h1sv[hp]) ? W1[src * DIM + col] : 0.f;
        w1p[i] = __float2bfloat16(v);
        if (col == 0) b1p[hp] = b1[src];
    }
}

// ---------------------------------------------------------------- spline eval
// p[0..7]=uw, p[8..15]=uh, p[16..24]=ud. Verified rounds 2-9 (fast-math r9).
__device__ __forceinline__ void spline_eval(const float* __restrict__ p,
                                            float xv, float& yout, float& lout) {
    float cw[NK + 1], ch[NK + 1];
    {
        float mx = p[0];
        #pragma unroll
        for (int j = 1; j < NK; j++) mx = fmaxf(mx, p[j]);
        float e[NK], s = 0.f;
        #pragma unroll
        for (int j = 0; j < NK; j++) { e[j] = fexp(p[j] - mx); s += e[j]; }
        const float inv = fdiv(1.f, s);
        cw[0] = 0.f;
        #pragma unroll
        for (int j = 0; j < NK; j++) cw[j + 1] = cw[j] + (0.001f + 0.992f * e[j] * inv);
    }
    {
        float mx = p[8];
        #pragma unroll
        for (int j = 1; j < NK; j++) mx = fmaxf(mx, p[8 + j]);
        float e[NK], s = 0.f;
        #pragma unroll
        for (int j = 0; j < NK; j++) { e[j] = fexp(p[8 + j] - mx); s += e[j]; }
        const float inv = fdiv(1.f, s);
        ch[0] = 0.f;
        #pragma unroll
        for (int j = 0; j < NK; j++) ch[j + 1] = ch[j] + (0.001f + 0.992f * e[j] * inv);
    }
    const float icw = fdiv(1.f, fmaxf(cw[NK], 1e-12f));
    const float ich = fdiv(1.f, fmaxf(ch[NK], 1e-12f));

    const bool inside = (xv >= -3.f) && (xv <= 3.f);
    float xs = (xv + 3.f) * (1.f / 6.f);
    xs = fminf(fmaxf(xs, 0.f), 1.f);
    const float xsc = xs * cw[NK];

    float xk = 0.f, wk = cw[1], yk = 0.f, hk = ch[1];
    float uda = p[16], udb = p[17];
    #pragma unroll
    for (int j = 1; j < NK; j++) {
        const bool c = (xsc >= cw[j]);
        xk  = c ? cw[j] : xk;
        wk  = c ? (cw[j + 1] - cw[j]) : wk;
        yk  = c ? ch[j] : yk;
        hk  = c ? (ch[j + 1] - ch[j]) : hk;
        uda = c ? p[16 + j] : uda;
        udb = c ? p[17 + j] : udb;
    }
    xk *= icw; wk *= icw;
    yk *= ich; hk *= ich;

    const float dk  = 0.001f + ((uda > 20.f) ? uda : flog(1.f + fexp(uda)));
    const float dk1 = 0.001f + ((udb > 20.f) ? udb : flog(1.f + fexp(udb)));

    float t = fdiv(xs - xk, wk + 1e-12f);
    t = fminf(fmaxf(t, 0.f), 1.f);
    const float a   = fdiv(hk + 1e-12f, wk + 1e-12f);
    const float omt = 1.f - t;
    const float tt1 = t * omt;
    const float num = a * t * t + dk * tt1;
    const float den = a + (dk + dk1 - 2.f * a) * tt1;
    const float s   = fdiv(num, den + 1e-12f);
    const float y   = (yk + hk * s) * 6.f - 3.f;
    const float dnum = a * a * (dk1 * t * t + 2.f * a * tt1 + dk * omt * omt);
    const float dydx = fdiv(dnum, den * den + 1e-12f);

    yout = inside ? y : xv;
    lout = inside ? flog(fmaxf(dydx, 1e-12f)) : 0.f;
}

// ---------------------------------------------------------------- GEMM (1,2)
__global__ __launch_bounds__(256, 4) void gemm_bt_kernel(
    const unsigned short* __restrict__ A,
    const unsigned short* __restrict__ Bw,
    const float* __restrict__ bias,
    const int* __restrict__ klim,
    __hip_bfloat16* __restrict__ Cout,
    int M, int N, int Kd)
{
    constexpr int BM = 128, BN = 128, BK = 64;
    __shared__ unsigned short As[BM * BK];
    __shared__ unsigned short Bs[BN * BK];

    const int bid = blockIdx.y * gridDim.x + blockIdx.x;
    const int GY  = (gridDim.y >= 16) ? 16 : gridDim.y;
    const int per_group = gridDim.x * GY;
    const int g  = bid / per_group;
    const int rr = bid % per_group;
    const int bn = (gridDim.x - 1 - rr / GY) * BN;    // long-K (high bn) first
    const int bm = (g * GY + (rr % GY)) * BM;
    const int Klim = klim[bn >> 7];

    const int t    = threadIdx.x;
    const int lane = t & 63;
    const int w    = t >> 6;
    const int wr   = (w >> 1) * 64;
    const int wc   = (w & 1) * 64;
    const int lr   = lane & 15;
    const int quad = lane >> 4;
    const int lxor = lr & 7;

    floatx4 acc[4][4] = {};

    const int lrow = lane >> 3;
    const int lcol = ((lane & 7) ^ lrow) * 8;

    for (int k0 = 0; k0 < Klim; k0 += BK) {
        __syncthreads();
        #pragma unroll
        for (int p = 0; p < 4; p++) {
            const int q = w * 4 + p;
            const int r = q * 8 + lrow;
            async_copy16(&A[(size_t)(bm + r) * Kd + k0 + lcol],
                         &As[q * 512 + lane * 8]);
            async_copy16(&Bw[(size_t)(bn + r) * Kd + k0 + lcol],
                         &Bs[q * 512 + lane * 8]);
        }
        __syncthreads();
        #pragma unroll
        for (int ks = 0; ks < BK; ks += 32) {
            const int cbase = (ks >> 3) + quad;
            const int coff  = (cbase ^ lxor) * 8;
            short8 af[4], bfr[4];
            #pragma unroll
            for (int i = 0; i < 4; i++)
                af[i] = *(const short8*)&As[(wr + i * 16 + lr) * BK + coff];
            #pragma unroll
            for (int j = 0; j < 4; j++)
                bfr[j] = *(const short8*)&Bs[(wc + j * 16 + lr) * BK + coff];
            #pragma unroll
            for (int i = 0; i < 4; i++)
                #pragma unroll
                for (int j = 0; j < 4; j++)
                    acc[i][j] = __builtin_amdgcn_mfma_f32_16x16x32_bf16(
                        af[i], bfr[j], acc[i][j], 0, 0, 0);
        }
    }

    #pragma unroll
    for (int j = 0; j < 4; j++) {
        const int col = bn + wc + j * 16 + lr;
        const float bv = bias[col];
        #pragma unroll
        for (int i = 0; i < 4; i++) {
            const int rowb = bm + wr + i * 16 + quad * 4;
            #pragma unroll
            for (int r = 0; r < 4; r++) {
                float v = acc[i][j][r] + bv;
                v = v * fdiv(1.f, 1.f + fexp(-v));    // fast silu
                Cout[(size_t)(rowb + r) * N + col] = __float2bfloat16(v);
            }
        }
    }
}

// ---------------------------------------------------------------- GEMM3+spline
__global__ __launch_bounds__(256, 4) void gemm3_spline_kernel(
    const unsigned short* __restrict__ A,    // h2b M x HID (perm2 col order)
    const unsigned short* __restrict__ Bw,   // w3p NP x HID (perm2 col order)
    const float* __restrict__ b3,            // N3 (original layout)
    const int* __restrict__ klim,            // [26]
    const float* __restrict__ x,             // M x DIM fp32
    float* __restrict__ out,                 // M x DIM
    float* __restrict__ lad,                 // M, pre-zeroed
    int M)
{
    constexpr int BM = 128, BN = 128, BK = 64, Kd = HID;
    constexpr int LSE = 133;                          // epilogue stride
    __shared__ __align__(16) char smem[64 * LSE * 4 + 128 * 4]; // 34,560 B
    unsigned short* As = (unsigned short*)smem;       // 16 KB
    unsigned short* Bs = (unsigned short*)(smem + BM * BK * 2);
    float* eb     = (float*)smem;
    float* ladacc = (float*)(smem + 64 * LSE * 4);    // [128]

    const int bid = blockIdx.y * gridDim.x + blockIdx.x;
    const int GY  = 16;                               // gridDim.y = 128
    const int per_group = gridDim.x * GY;
    const int g  = bid / per_group;
    const int rr = bid % per_group;
    const int tile = 25 - rr / GY;                    // long-K tiles first
    const int bn = tile * BN;
    const int bm = (g * GY + (rr % GY)) * BM;
    const int Klim = klim[tile];

    const int t    = threadIdx.x;
    const int lane = t & 63;
    const int w    = t >> 6;
    const int wr   = (w >> 1) * 64;
    const int wc   = (w & 1) * 64;
    const int lr   = lane & 15;
    const int quad = lane >> 4;
    const int lxor = lr & 7;

    if (t < 128) ladacc[t] = 0.f;

    floatx4 acc[4][4] = {};

    const int lrow = lane >> 3;
    const int lcol = ((lane & 7) ^ lrow) * 8;

    for (int k0 = 0; k0 < Klim; k0 += BK) {
        __syncthreads();
        #pragma unroll
        for (int p = 0; p < 4; p++) {
            const int q = w * 4 + p;
            const int r = q * 8 + lrow;
            async_copy16(&A[(size_t)(bm + r) * Kd + k0 + lcol],
                         &As[q * 512 + lane * 8]);
            async_copy16(&Bw[(size_t)(bn + r) * Kd + k0 + lcol],
                         &Bs[q * 512 + lane * 8]);
        }
        __syncthreads();
        #pragma unroll
        for (int ks = 0; ks < BK; ks += 32) {
            const int cbase = (ks >> 3) + quad;
            const int coff  = (cbase ^ lxor) * 8;
            short8 af[4], bfr[4];
            #pragma unroll
            for (int i = 0; i < 4; i++)
                af[i] = *(const short8*)&As[(wr + i * 16 + lr) * BK + coff];
            #pragma unroll
            for (int j = 0; j < 4; j++)
                bfr[j] = *(const short8*)&Bs[(wc + j * 16 + lr) * BK + coff];
            #pragma unroll
            for (int i = 0; i < 4; i++)
                #pragma unroll
                for (int j = 0; j < 4; j++)
                    acc[i][j] = __builtin_amdgcn_mfma_f32_16x16x32_bf16(
                        af[i], bfr[j], acc[i][j], 0, 0, 0);
        }
    }

    // ---- fused epilogue: two 64-row halves ----
    #pragma unroll 1
    for (int h = 0; h < 2; h++) {
        __syncthreads();
        if ((w >> 1) == h) {
            #pragma unroll
            for (int j = 0; j < 4; j++) {
                const int s = wc + j * 16 + lr;
                const float bv = (s < 125) ? b3[tile * 125 + s] : 0.f;
                #pragma unroll
                for (int i = 0; i < 4; i++) {
                    const int lrw = i * 16 + quad * 4;
                    #pragma unroll
                    for (int r2 = 0; r2 < 4; r2++)
                        eb[(lrw + r2) * LSE + s] = acc[i][j][r2] + bv;
                }
            }
        }
        __syncthreads();
        #pragma unroll 1
        for (int q = t; q < 320; q += 256) {
            const int r  = q / 5;
            const int ds = q % 5;
            const int dim = tile * 5 + ds;
            if (dim < DIM) {
                const float* p = eb + r * LSE + ds * 25;
                const int grow = bm + h * 64 + r;
                const float xv = x[(size_t)grow * DIM + dim];
                float y, l;
                spline_eval(p, xv, y, l);
                out[(size_t)grow * DIM + dim] = y;
                atomicAdd(&ladacc[h * 64 + r], l);
            }
        }
    }
    __syncthreads();
    if (t < 128) atomicAdd(&lad[bm + t], ladacc[t]);
}

// ---------------------------------------------------------------- launch
extern "C" void kernel_launch(void* const* d_in, const int* in_sizes, int n_in,
                              void* d_out, int out_size, void* d_ws, size_t ws_size,
                              hipStream_t stream) {
    const float* x  = (const float*)d_in[0];
    const float* W1 = (const float*)d_in[1];
    const float* b1 = (const float*)d_in[2];
    const float* W2 = (const float*)d_in[3];
    const float* b2 = (const float*)d_in[4];
    const float* W3 = (const float*)d_in[5];
    const float* b3 = (const float*)d_in[6];
    const float* m1 = (const float*)d_in[7];
    const float* m3 = (const float*)d_in[9];

    // workspace: ~81 MB + small arrays
    char* ws = (char*)d_ws;
    const size_t OFF_W1B = 0;
    const size_t OFF_W2B = OFF_W1B + (size_t)HID * DIM * 2;
    const size_t OFF_W3P = OFF_W2B + (size_t)HID * HID * 2;
    const size_t OFF_XB  = OFF_W3P + (size_t)NP * HID * 2;
    const size_t OFF_H1B = OFF_XB  + (size_t)BATCH * DIM * 2;
    const size_t OFF_H2B = OFF_H1B + (size_t)BATCH * HID * 2;
    const size_t OFF_SML = OFF_H2B + (size_t)BATCH * HID * 2;

    __hip_bfloat16* w1p = (__hip_bfloat16*)(ws + OFF_W1B);
    __hip_bfloat16* w2p = (__hip_bfloat16*)(ws + OFF_W2B);
    __hip_bfloat16* w3p = (__hip_bfloat16*)(ws + OFF_W3P);
    __hip_bfloat16* xb  = (__hip_bfloat16*)(ws + OFF_XB);
    __hip_bfloat16* h1b = (__hip_bfloat16*)(ws + OFF_H1B);
    __hip_bfloat16* h2b = (__hip_bfloat16*)(ws + OFF_H2B);

    float* b1p   = (float*)(ws + OFF_SML);
    float* b2p   = b1p + HID;
    int*   h1i   = (int*)(b2p + HID);
    int*   h2i   = h1i + HID;
    int*   perm1 = h2i + HID;
    int*   perm2 = perm1 + HID;
    int*   h1sv  = perm2 + HID;
    int*   h2sv  = h1sv + HID;
    int*   klim1 = h2sv + HID;
    int*   klim2 = klim1 + 8;
    int*   klim3 = klim2 + 8;

    float* out_p = (float*)d_out;
    float* lad_p = out_p + (size_t)BATCH * DIM;

    // 3 prep dispatches (was 6)
    pre_kernel<<<516 + (BATCH * DIM) / 256, 256, 0, stream>>>(
        m1, m3, x, h1i, h2i, xb, lad_p);
    sort_kernel<<<1, 1024, 0, stream>>>(h1i, h2i, perm1, perm2, h1sv, h2sv,
                                        klim1, klim2, klim3);
    megaprep_kernel<<<HID + NP + (HID * DIM) / 256, 256, 0, stream>>>(
        W1, b1, W2, b2, W3, perm1, perm2, h1sv, h2sv,
        w1p, b1p, w2p, b2p, w3p);

    // GEMMs (per-tile K bounds from sorted-mask prefixes)
    gemm_bt_kernel<<<dim3(HID / 128, BATCH / 128), 256, 0, stream>>>(
        (const unsigned short*)xb, (const unsigned short*)w1p, b1p, klim1, h1b,
        BATCH, HID, DIM);
    gemm_bt_kernel<<<dim3(HID / 128, BATCH / 128), 256, 0, stream>>>(
        (const unsigned short*)h1b, (const unsigned short*)w2p, b2p, klim2, h2b,
        BATCH, HID, HID);
    gemm3_spline_kernel<<<dim3(NP / 128, BATCH / 128), 256, 0, stream>>>(
        (const unsigned short*)h2b, (const unsigned short*)w3p, b3, klim3, x,
        out_p, lad_p, BATCH);
}